// Round 3
// baseline (5394.789 us; speedup 1.0000x reference)
//
#include <hip/hip_runtime.h>
#include <hip/hip_bf16.h>

// ============================================================================
// seq2seq + attention on MI355X.  B=32, Te=64, Td=32 (31 steps), E=256, H=512,
// V=32000.  Round 3: fix barrier OOB (bar+64 overran the 256-byte barrier
// allocation and aliased XF -> decoder deadlock).  Otherwise identical to the
// round-2 design: megakernels + grid barrier, LDS weight preload, df-phase
// eliminated via EFG = EF @ [W_df | b_df]^T precompute, XCD-swizzled logits.
// ============================================================================

typedef __attribute__((ext_vector_type(8))) short bfrag_t;
typedef __attribute__((ext_vector_type(4))) float f4_t;

static __device__ __forceinline__ float bf2f(unsigned short u) {
  union { float f; unsigned int i; } v; v.i = ((unsigned int)u) << 16; return v.f;
}
static __device__ __forceinline__ unsigned short f2bf(float f) {
  union { float f; unsigned int i; } v; v.f = f;
  unsigned int r = v.i + 0x7FFFu + ((v.i >> 16) & 1u);  // RNE
  return (unsigned short)(r >> 16);
}
static __device__ __forceinline__ unsigned int pack_bf2(float lo, float hi) {
  __hip_bfloat162 h2 = __float22bfloat162_rn(make_float2(lo, hi));
  union { __hip_bfloat162 h; unsigned int u; } cv; cv.h = h2;
  return cv.u;
}
static __device__ __forceinline__ float sigm(float x) { return 1.f / (1.f + expf(-x)); }

#define GLDS16(g, l)                                                        \
  __builtin_amdgcn_global_load_lds(                                         \
      (const __attribute__((address_space(1))) void*)(g),                   \
      (__attribute__((address_space(3))) void*)(l), 16, 0, 0)

// ---------------------------------------------------------------------------
// Device-scope grid barrier (sense-reversal).  bar[0]=count, bar[1]=gen.
// Requires all nblk blocks co-resident (grid <= 256 blocks, 1 block/CU fits).
// ---------------------------------------------------------------------------
static __device__ __forceinline__ void gbar(unsigned* bar, unsigned nblk) {
  __syncthreads();
  if (threadIdx.x == 0) {
    __threadfence();  // device-scope release of this block's writes
    unsigned g = __hip_atomic_load(bar + 1, __ATOMIC_SEQ_CST, __HIP_MEMORY_SCOPE_AGENT);
    unsigned a = __hip_atomic_fetch_add(bar, 1u, __ATOMIC_SEQ_CST, __HIP_MEMORY_SCOPE_AGENT);
    if (a == nblk - 1u) {
      __hip_atomic_store(bar, 0u, __ATOMIC_SEQ_CST, __HIP_MEMORY_SCOPE_AGENT);
      __hip_atomic_store(bar + 1, g + 1u, __ATOMIC_SEQ_CST, __HIP_MEMORY_SCOPE_AGENT);
    } else {
      while (__hip_atomic_load(bar + 1, __ATOMIC_ACQUIRE, __HIP_MEMORY_SCOPE_AGENT) == g)
        __builtin_amdgcn_s_sleep(1);
    }
  }
  __syncthreads();
}

// ---------------------------------------------------------------------------
// C = A(bf16, MxK, lda) @ B(fp32 NxldB rows, +bcol0)^T + bias.
// 128x128 tile, BK=32, 4 waves.  1D grid, optional XCD swizzle (grid%8==0).
// obf: output bf16 instead of fp32.
// ---------------------------------------------------------------------------
__global__ __launch_bounds__(256) void gemm_bt_kernel(
    const unsigned short* __restrict__ A, int lda,
    const float* __restrict__ B, int ldb, int bcol0,
    const float* __restrict__ bias, void* __restrict__ Cv, int ldc,
    int Mvalid, int K, int Mt, int swz, int obf) {
  __shared__ unsigned short As[128 * 32];
  __shared__ unsigned short Bs[128 * 32];
  int id = blockIdx.x;
  if (swz) { int x = id & 7; id = x * ((int)gridDim.x >> 3) + (id >> 3); }
  const int mb = id % Mt, nb = id / Mt;
  const int m0 = mb * 128, n0 = nb * 128;
  const int tid = threadIdx.x;
  const int w = tid >> 6, lane = tid & 63;
  const int wr = (w >> 1) * 64, wc = (w & 1) * 64;
  const int l15 = lane & 15, l4 = lane >> 4;

  const int arow = w * 16 + (lane >> 2);
  const int acol = (lane & 3) * 8;
  const unsigned short* Ag = A + (size_t)(m0 + arow) * lda + acol;

  const int brow = tid >> 1;
  const int bcol = (tid & 1) * 16;
  const float* Bg = B + (size_t)(n0 + brow) * ldb + bcol0 + bcol;
  unsigned short* Bsw = Bs + brow * 32 + bcol;

  f4_t acc[4][4];
#pragma unroll
  for (int i = 0; i < 4; ++i)
#pragma unroll
    for (int j = 0; j < 4; ++j) {
      acc[i][j].x = 0.f; acc[i][j].y = 0.f; acc[i][j].z = 0.f; acc[i][j].w = 0.f;
    }

  for (int kt = 0; kt < K; kt += 32) {
    GLDS16(Ag + kt, As + w * 512);
    GLDS16(Ag + (size_t)64 * lda + kt, As + (4 + w) * 512);
    float4 q0 = *(const float4*)(Bg + kt);
    float4 q1 = *(const float4*)(Bg + kt + 4);
    float4 q2 = *(const float4*)(Bg + kt + 8);
    float4 q3 = *(const float4*)(Bg + kt + 12);
    union { unsigned int u[8]; uint4 q[2]; } pk;
    pk.u[0] = pack_bf2(q0.x, q0.y); pk.u[1] = pack_bf2(q0.z, q0.w);
    pk.u[2] = pack_bf2(q1.x, q1.y); pk.u[3] = pack_bf2(q1.z, q1.w);
    pk.u[4] = pack_bf2(q2.x, q2.y); pk.u[5] = pack_bf2(q2.z, q2.w);
    pk.u[6] = pack_bf2(q3.x, q3.y); pk.u[7] = pack_bf2(q3.z, q3.w);
    *(uint4*)(Bsw) = pk.q[0];
    *(uint4*)(Bsw + 8) = pk.q[1];
    __syncthreads();
    bfrag_t af[4], bfv[4];
#pragma unroll
    for (int m = 0; m < 4; ++m)
      af[m] = *(const bfrag_t*)(As + (wr + m * 16 + l15) * 32 + l4 * 8);
#pragma unroll
    for (int n = 0; n < 4; ++n)
      bfv[n] = *(const bfrag_t*)(Bs + (wc + n * 16 + l15) * 32 + l4 * 8);
#pragma unroll
    for (int m = 0; m < 4; ++m)
#pragma unroll
      for (int n = 0; n < 4; ++n)
        acc[m][n] = __builtin_amdgcn_mfma_f32_16x16x32_bf16(af[m], bfv[n], acc[m][n], 0, 0, 0);
    __syncthreads();
  }

  const int crb = l4 * 4;
  float* Cf = (float*)Cv;
  unsigned short* Ch = (unsigned short*)Cv;
#pragma unroll
  for (int m = 0; m < 4; ++m)
#pragma unroll
    for (int n = 0; n < 4; ++n)
#pragma unroll
      for (int r = 0; r < 4; ++r) {
        int gr = m0 + wr + m * 16 + crb + r;
        if (gr < Mvalid) {
          int gc = n0 + wc + n * 16 + l15;
          float v = acc[m][n][r] + (bias ? bias[gc] : 0.f);
          if (obf) Ch[(size_t)gr * ldc + gc] = f2bf(v);
          else     Cf[(size_t)gr * ldc + gc] = v;
        }
      }
}

// ---------------------------------------------------------------------------
// Embedding gathers -> bf16
// ---------------------------------------------------------------------------
__global__ void gather_enc_kernel(const int* __restrict__ texts,
                                  const float* __restrict__ table,
                                  unsigned short* __restrict__ out) {
  const int row = blockIdx.x;
  const int tok = texts[row];
  const float4 v = *(const float4*)(table + (size_t)tok * 256 + threadIdx.x * 4);
  unsigned short* o = out + (size_t)row * 256 + threadIdx.x * 4;
  o[0] = f2bf(v.x); o[1] = f2bf(v.y); o[2] = f2bf(v.z); o[3] = f2bf(v.w);
}

__global__ void gather_dec_kernel(const int* __restrict__ texts,
                                  const float* __restrict__ table,
                                  unsigned short* __restrict__ out) {
  const int row = blockIdx.x;
  unsigned short* o = out + (size_t)row * 256 + threadIdx.x * 4;
  if (row >= 992) { o[0] = 0; o[1] = 0; o[2] = 0; o[3] = 0; return; }
  const int b = row / 31, t2 = row - b * 31;
  const int tok = texts[b * 32 + t2];
  const float4 v = *(const float4*)(table + (size_t)tok * 256 + threadIdx.x * 4);
  o[0] = f2bf(v.x); o[1] = f2bf(v.y); o[2] = f2bf(v.z); o[3] = f2bf(v.w);
}

// ---------------------------------------------------------------------------
// W_dfT[n][j] = W_df[j][n] (1024x1024), row 1024 = b_df.  Rows 1025..1151
// of the destination are left as-is (padding, consumed only into unused cols).
// ---------------------------------------------------------------------------
__global__ __launch_bounds__(256) void wdf_t_kernel(
    const float* __restrict__ W_df, const float* __restrict__ b_df,
    float* __restrict__ WT) {
  const int bid = blockIdx.x;
  if (bid < 1024) {
    __shared__ float tl[32][33];
    const int tx = (bid & 31) * 32, ty = (bid >> 5) * 32;
    const int r = threadIdx.x >> 5, c = threadIdx.x & 31;
#pragma unroll
    for (int i = 0; i < 4; ++i)
      tl[r + i * 8][c] = W_df[(size_t)(ty + r + i * 8) * 1024 + tx + c];
    __syncthreads();
#pragma unroll
    for (int i = 0; i < 4; ++i)
      WT[(size_t)(tx + r + i * 8) * 1024 + ty + c] = tl[c][r + i * 8];
  } else {
    for (int i = threadIdx.x; i < 1024; i += 256)
      WT[(size_t)1024 * 1024 + i] = b_df[i];
  }
}

// ---------------------------------------------------------------------------
// Encoder megakernel: 256 blocks (dir = bi>>7, 4 units each), 64 steps,
// per-direction 128-block grid barrier.  Whh tile (16x512) preloaded in LDS.
// ---------------------------------------------------------------------------
__global__ __launch_bounds__(256) void mega_enc_kernel(
    const float* __restrict__ XF, const float* __restrict__ XB,
    const float* __restrict__ Whh_f, const float* __restrict__ Whh_b,
    const float* __restrict__ mask, float* __restrict__ HENC,
    unsigned short* __restrict__ ENCO, float* __restrict__ HFIN,
    unsigned* bar) {
  const int bi = blockIdx.x;
  const int dir = bi >> 7;
  const int u0 = (bi & 127) * 4;
  const int tid = threadIdx.x;
  const int j = tid >> 4, bp = tid & 15;
  const int gate = j >> 2, ul = j & 3;
  const int grow = gate * 512 + u0 + ul;
  const int b0 = bp * 2, b1 = b0 + 1;
  const float* X = dir ? XB : XF;
  const float* W = dir ? Whh_b : Whh_f;
  float* Hh = HENC + (size_t)dir * 65536;
  float* Hc = HENC + (size_t)dir * 65536 + 32768;
  unsigned* mybar = bar + dir * 64;  // 256 B apart per direction

  __shared__ float Wl[16][512];
  __shared__ float Hl[32][132];
  __shared__ float Gl[16][32];

  // Preload loop-invariant W tile: row r -> Whh row (r>>2)*512 + u0 + (r&3)
  for (int idx = tid; idx < 2048; idx += 256) {
    int r = idx >> 7, c = (idx & 127) * 4;
    *(float4*)&Wl[r][c] =
        *(const float4*)(W + (size_t)((r >> 2) * 512 + u0 + (r & 3)) * 512 + c);
  }

  const int sr = tid >> 5;          // staging row base (0..7)
  const int sc = (tid & 31) * 4;    // staging col (0..124)

  for (int s = 0; s < 64; ++s) {
    const int t = dir ? (63 - s) : s;
    const int pp = s & 1;
    const float* Hcur = Hh + pp * 16384;
    float4 pf0 = *(const float4*)(Hcur + (sr + 0) * 512 + sc);
    float4 pf1 = *(const float4*)(Hcur + (sr + 8) * 512 + sc);
    float4 pf2 = *(const float4*)(Hcur + (sr + 16) * 512 + sc);
    float4 pf3 = *(const float4*)(Hcur + (sr + 24) * 512 + sc);
    float a0 = X[((size_t)b0 * 64 + t) * 2048 + grow];
    float a1 = X[((size_t)b1 * 64 + t) * 2048 + grow];
    for (int kc = 0; kc < 512; kc += 128) {
      *(float4*)&Hl[sr + 0][sc] = pf0;
      *(float4*)&Hl[sr + 8][sc] = pf1;
      *(float4*)&Hl[sr + 16][sc] = pf2;
      *(float4*)&Hl[sr + 24][sc] = pf3;
      __syncthreads();
      if (kc < 384) {  // prefetch next chunk while computing this one
        pf0 = *(const float4*)(Hcur + (sr + 0) * 512 + kc + 128 + sc);
        pf1 = *(const float4*)(Hcur + (sr + 8) * 512 + kc + 128 + sc);
        pf2 = *(const float4*)(Hcur + (sr + 16) * 512 + kc + 128 + sc);
        pf3 = *(const float4*)(Hcur + (sr + 24) * 512 + kc + 128 + sc);
      }
#pragma unroll
      for (int k = 0; k < 128; k += 4) {
        float4 wv = *(const float4*)&Wl[j][kc + k];
        float4 h0 = *(const float4*)&Hl[b0][k];
        float4 h1 = *(const float4*)&Hl[b1][k];
        a0 += wv.x * h0.x + wv.y * h0.y + wv.z * h0.z + wv.w * h0.w;
        a1 += wv.x * h1.x + wv.y * h1.y + wv.z * h1.z + wv.w * h1.w;
      }
      __syncthreads();
    }
    Gl[j][b0] = a0;
    Gl[j][b1] = a1;
    __syncthreads();
    if (tid < 128) {
      const int b = tid & 31, uo = tid >> 5;
      const int u = u0 + uo;
      float gi = Gl[uo][b], gf = Gl[4 + uo][b], gg = Gl[8 + uo][b], go = Gl[12 + uo][b];
      float c_old = Hc[pp * 16384 + b * 512 + u];
      float h_old = Hh[pp * 16384 + b * 512 + u];
      float cn = sigm(gf) * c_old + sigm(gi) * tanhf(gg);
      float hn = sigm(go) * tanhf(cn);
      float m = mask[b * 64 + t];
      float hmix = m * hn + (1.f - m) * h_old;
      float cmix = m * cn + (1.f - m) * c_old;
      Hh[(pp ^ 1) * 16384 + b * 512 + u] = hmix;
      Hc[(pp ^ 1) * 16384 + b * 512 + u] = cmix;
      ENCO[((size_t)b * 64 + t) * 1024 + dir * 512 + u] = f2bf(hmix * m);
      if (s == 63) {
        HFIN[dir * 16384 + b * 512 + u] = hmix;
        HFIN[(2 + dir) * 16384 + b * 512 + u] = cmix;
      }
    }
    if (s < 63) gbar(mybar, 128);
  }
}

// ---------------------------------------------------------------------------
// Decoder megakernel: 128 blocks.  init phase, then 31 x {gates, attn}.
// Gates weight tile (16x1536 = [Wih_d[:,256:]|Whh_d] rows) preloaded in LDS.
// Attention uses EFG (EF @ [W_df|b_df]^T precomputed) -> no df phase.
// ---------------------------------------------------------------------------
__global__ __launch_bounds__(256) void mega_dec_kernel(
    const float* __restrict__ HFIN, const float* __restrict__ W_h,
    const float* __restrict__ b_h, const float* __restrict__ W_c,
    const float* __restrict__ b_c, const float* __restrict__ XD,
    const float* __restrict__ Wih_d, const float* __restrict__ Whh_d,
    const float* __restrict__ EFG, const unsigned short* __restrict__ ENCO,
    const float* __restrict__ mask, float* __restrict__ HDEC,
    float* __restrict__ CTX, unsigned short* __restrict__ ACAT,
    unsigned* bar) {
  const int bi = blockIdx.x;
  const int tid = threadIdx.x;

  __shared__ float Wg[16][1536];   // 96 KB: gates weights, loop-invariant
  __shared__ float Wi[8][132];     // init-phase W chunk
  __shared__ float Xl[32][132];
  __shared__ float Gl[16][32];
  __shared__ float hcl[1024];
  __shared__ float scl[64];
  __shared__ float al[64];

  const int u0 = bi * 4;

  // Preload gates W tile: row r -> wrow=(r>>2)*512+u0+(r&3); cols 0..1023 from
  // Wih_d[wrow][256+*], cols 1024..1535 from Whh_d[wrow][*].
  for (int idx = tid; idx < 6144; idx += 256) {
    int r = idx / 384, c = (idx % 384) * 4;
    int wrow = (r >> 2) * 512 + u0 + (r & 3);
    float4 v;
    if (c < 1024) v = *(const float4*)(Wih_d + (size_t)wrow * 1280 + 256 + c);
    else          v = *(const float4*)(Whh_d + (size_t)wrow * 512 + (c - 1024));
    *(float4*)&Wg[r][c] = v;
  }

  const int sr = tid >> 5, sc = (tid & 31) * 4;

  // ---- init: dec_h = relu([hf,hb]@W_h^T+b_h), dec_c likewise ----
  {
    const int mat = bi >> 6, j0i = (bi & 63) * 8;
    const int jj = tid >> 5, b = tid & 31;
    const float* Wm = mat ? W_c : W_h;
    const float* bias = mat ? b_c : b_h;
    const float* x0 = HFIN + (size_t)(mat ? 2 : 0) * 16384;
    const float* x1 = HFIN + (size_t)(mat ? 3 : 1) * 16384;
    float acc = 0.f;
    for (int kc = 0; kc < 1024; kc += 128) {
#pragma unroll
      for (int i = 0; i < 4; ++i) {
        int r = sr + i * 8;
        const float* src = (kc < 512) ? (x0 + r * 512 + kc + sc)
                                      : (x1 + r * 512 + (kc - 512) + sc);
        *(float4*)&Xl[r][sc] = *(const float4*)src;
      }
      {
        int r = tid >> 5, c = (tid & 31) * 4;
        *(float4*)&Wi[r][c] = *(const float4*)(Wm + (size_t)(j0i + r) * 1024 + kc + c);
      }
      __syncthreads();
#pragma unroll
      for (int k = 0; k < 128; k += 4) {
        float4 wv = *(const float4*)&Wi[jj][k];
        float4 xv = *(const float4*)&Xl[b][k];
        acc += wv.x * xv.x + wv.y * xv.y + wv.z * xv.z + wv.w * xv.w;
      }
      __syncthreads();
    }
    float v = acc + bias[j0i + jj];
    HDEC[(size_t)mat * 32768 + b * 512 + j0i + jj] = fmaxf(v, 0.f);
  }
  gbar(bar, 128);

  const int jj = tid >> 4, bp = tid & 15;
  const int gate = jj >> 2, ul = jj & 3;
  const int growD = gate * 512 + u0 + ul;
  const int b0 = bp * 2, b1 = b0 + 1;

  for (int t = 0; t < 31; ++t) {
    const int dp = t & 1, dpw = dp ^ 1;
    // ---- gates: g = XD + [ctx,h] @ Wg^T -> h,c update ----
    {
      const float* hsrc = HDEC + dp * 16384;
      const float* csrc = HDEC + 32768 + dp * 16384;
      const float* ctxsrc = CTX + dp * 32768;
      float a0 = XD[((size_t)b0 * 31 + t) * 2048 + growD];
      float a1 = XD[((size_t)b1 * 31 + t) * 2048 + growD];
      float4 pf0 = *(const float4*)(ctxsrc + (sr + 0) * 1024 + sc);
      float4 pf1 = *(const float4*)(ctxsrc + (sr + 8) * 1024 + sc);
      float4 pf2 = *(const float4*)(ctxsrc + (sr + 16) * 1024 + sc);
      float4 pf3 = *(const float4*)(ctxsrc + (sr + 24) * 1024 + sc);
      for (int kc = 0; kc < 1536; kc += 128) {
        *(float4*)&Xl[sr + 0][sc] = pf0;
        *(float4*)&Xl[sr + 8][sc] = pf1;
        *(float4*)&Xl[sr + 16][sc] = pf2;
        *(float4*)&Xl[sr + 24][sc] = pf3;
        __syncthreads();
        if (kc < 1408) {
          const int kn = kc + 128;
#define DECSRC(r) ((kn < 1024) ? (ctxsrc + (size_t)(r) * 1024 + kn + sc) \
                               : (hsrc + (size_t)(r) * 512 + (kn - 1024) + sc))
          pf0 = *(const float4*)DECSRC(sr);
          pf1 = *(const float4*)DECSRC(sr + 8);
          pf2 = *(const float4*)DECSRC(sr + 16);
          pf3 = *(const float4*)DECSRC(sr + 24);
#undef DECSRC
        }
#pragma unroll
        for (int k = 0; k < 128; k += 4) {
          float4 wv = *(const float4*)&Wg[jj][kc + k];
          float4 x0 = *(const float4*)&Xl[b0][k];
          float4 x1 = *(const float4*)&Xl[b1][k];
          a0 += wv.x * x0.x + wv.y * x0.y + wv.z * x0.z + wv.w * x0.w;
          a1 += wv.x * x1.x + wv.y * x1.y + wv.z * x1.z + wv.w * x1.w;
        }
        __syncthreads();
      }
      Gl[jj][b0] = a0;
      Gl[jj][b1] = a1;
      __syncthreads();
      if (tid < 128) {
        const int b = tid & 31, uo = tid >> 5;
        const int u = u0 + uo;
        float gi = Gl[uo][b], gf = Gl[4 + uo][b], gg = Gl[8 + uo][b], go = Gl[12 + uo][b];
        float c_old = csrc[b * 512 + u];
        float cn = sigm(gf) * c_old + sigm(gi) * tanhf(gg);
        float hn = sigm(go) * tanhf(cn);
        HDEC[dpw * 16384 + b * 512 + u] = hn;
        HDEC[32768 + dpw * 16384 + b * 512 + u] = cn;
        ACAT[((size_t)b * 31 + t) * 1536 + u] = f2bf(hn);
      }
    }
    gbar(bar, 128);
    // ---- attention (blocks 0..31, one batch each) ----
    if (bi < 32) {
      const int b = bi;
      const float* hsrcN = HDEC + dpw * 16384;
      const float* csrcN = HDEC + 32768 + dpw * 16384;
      {
        int c = tid * 4;
        float4 v = (c < 512) ? *(const float4*)(hsrcN + b * 512 + c)
                             : *(const float4*)(csrcN + b * 512 + (c - 512));
        *(float4*)&hcl[c] = v;
      }
      __syncthreads();
      {
        const int s = tid >> 2, part = tid & 3;
        const float* eg = EFG + ((size_t)b * 64 + s) * 1152 + part * 256;
        float acc = 0.f;
        for (int k = 0; k < 256; k += 4) {
          float4 e = *(const float4*)(eg + k);
          float4 d = *(const float4*)(&hcl[part * 256 + k]);
          acc += e.x * d.x + e.y * d.y + e.z * d.z + e.w * d.w;
        }
        acc += __shfl_xor(acc, 1);
        acc += __shfl_xor(acc, 2);
        if (part == 0)
          scl[s] = acc + EFG[((size_t)b * 64 + s) * 1152 + 1024];  // b_df term
      }
      __syncthreads();
      if (tid < 64) {
        float v = scl[tid];
        float mx = v;
#pragma unroll
        for (int o = 32; o >= 1; o >>= 1) mx = fmaxf(mx, __shfl_xor(mx, o));
        float e = expf(v - mx) * mask[b * 64 + tid];
        float sm = e;
#pragma unroll
        for (int o = 32; o >= 1; o >>= 1) sm += __shfl_xor(sm, o);
        al[tid] = e / sm;
      }
      __syncthreads();
      float c0 = 0.f, c1 = 0.f, c2 = 0.f, c3 = 0.f;
      for (int tp = 0; tp < 64; ++tp) {
        float a = al[tp];
        const unsigned short* eo = ENCO + ((size_t)b * 64 + tp) * 1024 + tid;
        c0 += a * bf2f(eo[0]);
        c1 += a * bf2f(eo[256]);
        c2 += a * bf2f(eo[512]);
        c3 += a * bf2f(eo[768]);
      }
      float* cp = CTX + dpw * 32768 + b * 1024;
      unsigned short* ap = ACAT + ((size_t)b * 31 + t) * 1536 + 512;
      cp[tid] = c0; cp[tid + 256] = c1; cp[tid + 512] = c2; cp[tid + 768] = c3;
      ap[tid] = f2bf(c0); ap[tid + 256] = f2bf(c1);
      ap[tid + 512] = f2bf(c2); ap[tid + 768] = f2bf(c3);
    }
    if (t < 30) gbar(bar, 128);
  }
}

// ============================================================================
extern "C" void kernel_launch(void* const* d_in, const int* in_sizes, int n_in,
                              void* d_out, int out_size, void* d_ws, size_t ws_size,
                              hipStream_t stream) {
  const int*   enc_texts = (const int*)  d_in[0];
  const float* enc_mask  = (const float*)d_in[1];
  const int*   dec_texts = (const int*)  d_in[2];
  const float* enc_emb   = (const float*)d_in[3];
  const float* dec_emb   = (const float*)d_in[4];
  const float* Wih_f = (const float*)d_in[5];
  const float* Whh_f = (const float*)d_in[6];
  const float* b_f   = (const float*)d_in[7];
  const float* Wih_b = (const float*)d_in[8];
  const float* Whh_b = (const float*)d_in[9];
  const float* b_b   = (const float*)d_in[10];
  const float* Wih_d = (const float*)d_in[11];
  const float* Whh_d = (const float*)d_in[12];
  const float* b_d   = (const float*)d_in[13];
  const float* W_h   = (const float*)d_in[14];
  const float* b_h   = (const float*)d_in[15];
  const float* W_c   = (const float*)d_in[16];
  const float* b_c   = (const float*)d_in[17];
  const float* W_df  = (const float*)d_in[18];
  const float* b_df  = (const float*)d_in[19];
  const float* W_ef  = (const float*)d_in[20];
  const float* b_ef  = (const float*)d_in[21];
  const float* W_out = (const float*)d_in[22];
  const float* b_out = (const float*)d_in[23];
  float* out = (float*)d_out;

  char* ws = (char*)d_ws;
  size_t off = 0;
  auto alloc = [&](size_t bytes) {
    char* p = ws + off;
    off += (bytes + 255) & ~(size_t)255;
    return p;
  };
  // --- zero-init group ---
  float* HENC = (float*)alloc((size_t)8 * 16384 * 4);   // [dir][h/c][pp]
  float* HDEC = (float*)alloc((size_t)4 * 16384 * 4);   // [h/c][pp]
  float* CTX  = (float*)alloc((size_t)2 * 32768 * 4);   // [pp]
  unsigned short* ACAT = (unsigned short*)alloc((size_t)1024 * 1536 * 2);
  unsigned* bar = (unsigned*)alloc(1024);  // 256 uints: enc@+0/+64, dec@+128
  size_t zbytes = off;
  // --- rest ---
  float* XF = (float*)alloc((size_t)2048 * 2048 * 4);
  float* XB = (float*)alloc((size_t)2048 * 2048 * 4);
  float* XD = (float*)alloc((size_t)1024 * 2048 * 4);
  unsigned short* EFb  = (unsigned short*)alloc((size_t)2048 * 1024 * 2);
  unsigned short* ENCO = (unsigned short*)alloc((size_t)2048 * 1024 * 2);
  unsigned short* EMBB = (unsigned short*)alloc((size_t)2048 * 256 * 2);
  unsigned short* DEMB = (unsigned short*)alloc((size_t)1024 * 256 * 2);
  float* HFIN = (float*)alloc((size_t)4 * 16384 * 4);
  // aliases (lifetimes: written after mega_enc consumed XF/XB)
  float* EFG = XF;   // 2048 x 1152 fp32 = 9.4 MB
  float* WT  = XB;   // 1152 x 1024 fp32 = 4.7 MB

  hipMemsetAsync(d_ws, 0, zbytes, stream);

  gather_enc_kernel<<<2048, 64, 0, stream>>>(enc_texts, enc_emb, EMBB);
  gather_dec_kernel<<<1024, 64, 0, stream>>>(dec_texts, dec_emb, DEMB);

  dim3 blk(256);
  // XF/XB = emb @ Wih^T + b ; XD = dec_emb @ Wih_d[:, :256]^T + b_d
  gemm_bt_kernel<<<256, blk, 0, stream>>>(EMBB, 256, Wih_f, 256, 0, b_f, XF, 2048, 2048, 256, 16, 0, 0);
  gemm_bt_kernel<<<256, blk, 0, stream>>>(EMBB, 256, Wih_b, 256, 0, b_b, XB, 2048, 2048, 256, 16, 0, 0);
  gemm_bt_kernel<<<128, blk, 0, stream>>>(DEMB, 256, Wih_d, 1280, 0, b_d, XD, 2048, 1024, 256, 8, 0, 0);

  mega_enc_kernel<<<256, blk, 0, stream>>>(XF, XB, Whh_f, Whh_b, enc_mask, HENC, ENCO, HFIN, bar);

  // W_dfT (+bias row), EFb = bf16(enc_output @ W_ef^T + b_ef), EFG = EFb @ WT^T
  wdf_t_kernel<<<1025, blk, 0, stream>>>(W_df, b_df, WT);
  gemm_bt_kernel<<<128, blk, 0, stream>>>(ENCO, 1024, W_ef, 1024, 0, b_ef, EFb, 1024, 2048, 1024, 16, 0, 1);
  gemm_bt_kernel<<<144, blk, 0, stream>>>(EFb, 1024, WT, 1024, 0, nullptr, EFG, 1152, 2048, 1024, 16, 0, 0);

  mega_dec_kernel<<<128, blk, 0, stream>>>(HFIN, W_h, b_h, W_c, b_c, XD, Wih_d, Whh_d,
                                           EFG, ENCO, enc_mask, HDEC, CTX, ACAT, bar + 128);

  // logits = [h, ctx] @ W_out^T + b_out  (97.5 GFLOP, XCD-swizzled)
  gemm_bt_kernel<<<2000, blk, 0, stream>>>(ACAT, 1536, W_out, 1536, 0, b_out, out, 32000, 992, 1536, 8, 1, 0);
}

// Round 5
// 2458.148 us; speedup vs baseline: 2.1947x; 2.1947x over previous
//
#include <hip/hip_runtime.h>
#include <hip/hip_bf16.h>

// ============================================================================
// seq2seq + attention on MI355X.  B=32, Te=64, Td=32 (31 steps), E=256, H=512,
// V=32000.  Round 5: fix mega_enc H-staging indexing (idx>>5/&31 was the
// round-3 float4 layout; bf16 uint4 layout needs idx>>6/&63 — the bug wrote
// LDS out of bounds and staged only half of H, corrupting the whole net).
// Design otherwise identical to round 4:
//   - monotonic relaxed-atomic grid barrier (one release/acquire fence pair)
//   - recurrent matvecs via bf16 MFMA, weights preconverted to bf16 LDS once
//   - h,c state fp32 in owner-thread registers; h transported bf16
//   - decoder gates B-matrix staged from ACAT[t-1] rows [h|ctx] bf16
//   - logits GEMM XCD-swizzled
// ============================================================================

typedef __attribute__((ext_vector_type(8))) short bfrag_t;
typedef __attribute__((ext_vector_type(4))) float f4_t;

static __device__ __forceinline__ float bf2f(unsigned short u) {
  union { float f; unsigned int i; } v; v.i = ((unsigned int)u) << 16; return v.f;
}
static __device__ __forceinline__ unsigned short f2bf(float f) {
  union { float f; unsigned int i; } v; v.f = f;
  unsigned int r = v.i + 0x7FFFu + ((v.i >> 16) & 1u);  // RNE
  return (unsigned short)(r >> 16);
}
static __device__ __forceinline__ unsigned int pack_bf2(float lo, float hi) {
  __hip_bfloat162 h2 = __float22bfloat162_rn(make_float2(lo, hi));
  union { __hip_bfloat162 h; unsigned int u; } cv; cv.h = h2;
  return cv.u;
}
static __device__ __forceinline__ float sigm(float x) { return 1.f / (1.f + expf(-x)); }

#define GLDS16(g, l)                                                        \
  __builtin_amdgcn_global_load_lds(                                         \
      (const __attribute__((address_space(1))) void*)(g),                   \
      (__attribute__((address_space(3))) void*)(l), 16, 0, 0)

// ---------------------------------------------------------------------------
// Grid barrier: monotonic counting.  Caller passes target = nblk * (#calls).
// One release fence before arrive, one acquire fence after spin completes;
// spin is RELAXED agent atomics (no per-poll L2 invalidation).
// ---------------------------------------------------------------------------
static __device__ __forceinline__ void gbar(unsigned* cnt, unsigned target) {
  __syncthreads();
  if (threadIdx.x == 0) {
    __builtin_amdgcn_fence(__ATOMIC_RELEASE, "agent");
    __hip_atomic_fetch_add(cnt, 1u, __ATOMIC_RELAXED, __HIP_MEMORY_SCOPE_AGENT);
    while (__hip_atomic_load(cnt, __ATOMIC_RELAXED, __HIP_MEMORY_SCOPE_AGENT) < target)
      __builtin_amdgcn_s_sleep(2);
    __builtin_amdgcn_fence(__ATOMIC_ACQUIRE, "agent");
  }
  __syncthreads();
}

// ---------------------------------------------------------------------------
// C = A(bf16, MxK, lda) @ B(fp32 NxldB rows, +bcol0)^T + bias.   (unchanged)
// ---------------------------------------------------------------------------
__global__ __launch_bounds__(256) void gemm_bt_kernel(
    const unsigned short* __restrict__ A, int lda,
    const float* __restrict__ B, int ldb, int bcol0,
    const float* __restrict__ bias, void* __restrict__ Cv, int ldc,
    int Mvalid, int K, int Mt, int swz, int obf) {
  __shared__ unsigned short As[128 * 32];
  __shared__ unsigned short Bs[128 * 32];
  int id = blockIdx.x;
  if (swz) { int x = id & 7; id = x * ((int)gridDim.x >> 3) + (id >> 3); }
  const int mb = id % Mt, nb = id / Mt;
  const int m0 = mb * 128, n0 = nb * 128;
  const int tid = threadIdx.x;
  const int w = tid >> 6, lane = tid & 63;
  const int wr = (w >> 1) * 64, wc = (w & 1) * 64;
  const int l15 = lane & 15, l4 = lane >> 4;

  const int arow = w * 16 + (lane >> 2);
  const int acol = (lane & 3) * 8;
  const unsigned short* Ag = A + (size_t)(m0 + arow) * lda + acol;

  const int brow = tid >> 1;
  const int bcol = (tid & 1) * 16;
  const float* Bg = B + (size_t)(n0 + brow) * ldb + bcol0 + bcol;
  unsigned short* Bsw = Bs + brow * 32 + bcol;

  f4_t acc[4][4];
#pragma unroll
  for (int i = 0; i < 4; ++i)
#pragma unroll
    for (int j = 0; j < 4; ++j) {
      acc[i][j].x = 0.f; acc[i][j].y = 0.f; acc[i][j].z = 0.f; acc[i][j].w = 0.f;
    }

  for (int kt = 0; kt < K; kt += 32) {
    GLDS16(Ag + kt, As + w * 512);
    GLDS16(Ag + (size_t)64 * lda + kt, As + (4 + w) * 512);
    float4 q0 = *(const float4*)(Bg + kt);
    float4 q1 = *(const float4*)(Bg + kt + 4);
    float4 q2 = *(const float4*)(Bg + kt + 8);
    float4 q3 = *(const float4*)(Bg + kt + 12);
    union { unsigned int u[8]; uint4 q[2]; } pk;
    pk.u[0] = pack_bf2(q0.x, q0.y); pk.u[1] = pack_bf2(q0.z, q0.w);
    pk.u[2] = pack_bf2(q1.x, q1.y); pk.u[3] = pack_bf2(q1.z, q1.w);
    pk.u[4] = pack_bf2(q2.x, q2.y); pk.u[5] = pack_bf2(q2.z, q2.w);
    pk.u[6] = pack_bf2(q3.x, q3.y); pk.u[7] = pack_bf2(q3.z, q3.w);
    *(uint4*)(Bsw) = pk.q[0];
    *(uint4*)(Bsw + 8) = pk.q[1];
    __syncthreads();
    bfrag_t af[4], bfv[4];
#pragma unroll
    for (int m = 0; m < 4; ++m)
      af[m] = *(const bfrag_t*)(As + (wr + m * 16 + l15) * 32 + l4 * 8);
#pragma unroll
    for (int n = 0; n < 4; ++n)
      bfv[n] = *(const bfrag_t*)(Bs + (wc + n * 16 + l15) * 32 + l4 * 8);
#pragma unroll
    for (int m = 0; m < 4; ++m)
#pragma unroll
      for (int n = 0; n < 4; ++n)
        acc[m][n] = __builtin_amdgcn_mfma_f32_16x16x32_bf16(af[m], bfv[n], acc[m][n], 0, 0, 0);
    __syncthreads();
  }

  const int crb = l4 * 4;
  float* Cf = (float*)Cv;
  unsigned short* Ch = (unsigned short*)Cv;
#pragma unroll
  for (int m = 0; m < 4; ++m)
#pragma unroll
    for (int n = 0; n < 4; ++n)
#pragma unroll
      for (int r = 0; r < 4; ++r) {
        int gr = m0 + wr + m * 16 + crb + r;
        if (gr < Mvalid) {
          int gc = n0 + wc + n * 16 + l15;
          float v = acc[m][n][r] + (bias ? bias[gc] : 0.f);
          if (obf) Ch[(size_t)gr * ldc + gc] = f2bf(v);
          else     Cf[(size_t)gr * ldc + gc] = v;
        }
      }
}

// ---------------------------------------------------------------------------
// Embedding gathers -> bf16   (unchanged)
// ---------------------------------------------------------------------------
__global__ void gather_enc_kernel(const int* __restrict__ texts,
                                  const float* __restrict__ table,
                                  unsigned short* __restrict__ out) {
  const int row = blockIdx.x;
  const int tok = texts[row];
  const float4 v = *(const float4*)(table + (size_t)tok * 256 + threadIdx.x * 4);
  unsigned short* o = out + (size_t)row * 256 + threadIdx.x * 4;
  o[0] = f2bf(v.x); o[1] = f2bf(v.y); o[2] = f2bf(v.z); o[3] = f2bf(v.w);
}

__global__ void gather_dec_kernel(const int* __restrict__ texts,
                                  const float* __restrict__ table,
                                  unsigned short* __restrict__ out) {
  const int row = blockIdx.x;
  unsigned short* o = out + (size_t)row * 256 + threadIdx.x * 4;
  if (row >= 992) { o[0] = 0; o[1] = 0; o[2] = 0; o[3] = 0; return; }
  const int b = row / 31, t2 = row - b * 31;
  const int tok = texts[b * 32 + t2];
  const float4 v = *(const float4*)(table + (size_t)tok * 256 + threadIdx.x * 4);
  o[0] = f2bf(v.x); o[1] = f2bf(v.y); o[2] = f2bf(v.z); o[3] = f2bf(v.w);
}

// ---------------------------------------------------------------------------
// W_dfT[n][j] = W_df[j][n] (1024x1024), row 1024 = b_df.   (unchanged)
// ---------------------------------------------------------------------------
__global__ __launch_bounds__(256) void wdf_t_kernel(
    const float* __restrict__ W_df, const float* __restrict__ b_df,
    float* __restrict__ WT) {
  const int bid = blockIdx.x;
  if (bid < 1024) {
    __shared__ float tl[32][33];
    const int tx = (bid & 31) * 32, ty = (bid >> 5) * 32;
    const int r = threadIdx.x >> 5, c = threadIdx.x & 31;
#pragma unroll
    for (int i = 0; i < 4; ++i)
      tl[r + i * 8][c] = W_df[(size_t)(ty + r + i * 8) * 1024 + tx + c];
    __syncthreads();
#pragma unroll
    for (int i = 0; i < 4; ++i)
      WT[(size_t)(tx + r + i * 8) * 1024 + ty + c] = tl[c][r + i * 8];
  } else {
    for (int i = threadIdx.x; i < 1024; i += 256)
      WT[(size_t)1024 * 1024 + i] = b_df[i];
  }
}

// ---------------------------------------------------------------------------
// Encoder megakernel (MFMA).  256 blocks: dir=bi>>7, 4 units each; 64 steps.
// ---------------------------------------------------------------------------
__global__ __launch_bounds__(256) void mega_enc_kernel(
    const float* __restrict__ XF, const float* __restrict__ XB,
    const float* __restrict__ Whh_f, const float* __restrict__ Whh_b,
    const float* __restrict__ mask,
    unsigned short* __restrict__ HBF,   // [dir][pp][32*512] bf16
    unsigned short* __restrict__ ENCO, float* __restrict__ HFIN,
    unsigned* bar) {
  const int bi = blockIdx.x;
  const int dir = bi >> 7;
  const int u0 = (bi & 127) * 4;
  const int tid = threadIdx.x;
  const float* X = dir ? XB : XF;
  const float* W = dir ? Whh_b : Whh_f;
  unsigned short* Hbf = HBF + dir * 32768;
  unsigned* cnt = bar + dir * 32;   // 128 B apart

  __shared__ unsigned short WA[16 * 520];   // row j=(gate*4+ul), padded stride
  __shared__ unsigned short HB[32 * 520];   // row = batch
  __shared__ float Gl[16][33];

  // one-time: Whh slice rows -> bf16 LDS.  row j -> Whh[(j>>2)*512+u0+(j&3)]
#pragma unroll
  for (int i = 0; i < 8; ++i) {
    int idx = tid + i * 256;               // 16 rows x 128 float4-cols
    int r = idx >> 7, c4 = idx & 127;
    const float4 v = *(const float4*)(W + (size_t)((r >> 2) * 512 + u0 + (r & 3)) * 512 + c4 * 4);
    *(uint2*)(WA + r * 520 + c4 * 4) = make_uint2(pack_bf2(v.x, v.y), pack_bf2(v.z, v.w));
  }
  __syncthreads();

  const int w = tid >> 6, lane = tid & 63;
  const int l15 = lane & 15, l4 = lane >> 4;

  bfrag_t afr[16];
  if (w < 2) {
#pragma unroll
    for (int kk = 0; kk < 16; ++kk)
      afr[kk] = *(const bfrag_t*)(WA + l15 * 520 + kk * 32 + l4 * 8);
  }

  const int ob = tid & 31, ouo = (tid >> 5) & 3;
  const int ou = u0 + ouo;
  float h_reg = 0.f, c_reg = 0.f;

  unsigned tgt = 0;
  for (int s = 0; s < 64; ++s) {
    const int t = dir ? (63 - s) : s;
    const int pp = s & 1;
    // owner prefetch: X gates + mask (consumed after MFMA)
    float xg0 = 0, xg1 = 0, xg2 = 0, xg3 = 0, mval = 0;
    if (tid < 128) {
      const float* xp = X + ((size_t)ob * 64 + t) * 2048 + ou;
      xg0 = xp[0]; xg1 = xp[512]; xg2 = xp[1024]; xg3 = xp[1536];
      mval = mask[ob * 64 + t];
    }
    // stage h (bf16, 32 rows x 512 shorts = 2048 uint4, 64 uint4/row)
    const unsigned short* hsrc = Hbf + pp * 16384;
#pragma unroll
    for (int i = 0; i < 8; ++i) {
      int idx = tid + i * 256;
      int r = idx >> 6, c = idx & 63;      // FIXED (was >>5 / &31: OOB + half-stage)
      uint4 v = *(const uint4*)(hsrc + r * 512 + c * 8);
      *(uint4*)(HB + r * 520 + c * 8) = v;
    }
    __syncthreads();
    if (w < 2) {
      f4_t ae = {0.f, 0.f, 0.f, 0.f}, ao = {0.f, 0.f, 0.f, 0.f};
#pragma unroll
      for (int kk = 0; kk < 16; kk += 2) {
        bfrag_t b0 = *(const bfrag_t*)(HB + (w * 16 + l15) * 520 + kk * 32 + l4 * 8);
        bfrag_t b1 = *(const bfrag_t*)(HB + (w * 16 + l15) * 520 + (kk + 1) * 32 + l4 * 8);
        ae = __builtin_amdgcn_mfma_f32_16x16x32_bf16(afr[kk], b0, ae, 0, 0, 0);
        ao = __builtin_amdgcn_mfma_f32_16x16x32_bf16(afr[kk + 1], b1, ao, 0, 0, 0);
      }
#pragma unroll
      for (int r = 0; r < 4; ++r)
        Gl[l4 * 4 + r][w * 16 + l15] = ae[r] + ao[r];
    }
    __syncthreads();
    if (tid < 128) {
      float gi = Gl[ouo][ob] + xg0;
      float gf = Gl[4 + ouo][ob] + xg1;
      float gg = Gl[8 + ouo][ob] + xg2;
      float go = Gl[12 + ouo][ob] + xg3;
      float cn = sigm(gf) * c_reg + sigm(gi) * tanhf(gg);
      float hn = sigm(go) * tanhf(cn);
      float hmix = mval * hn + (1.f - mval) * h_reg;
      float cmix = mval * cn + (1.f - mval) * c_reg;
      h_reg = hmix; c_reg = cmix;
      ENCO[((size_t)ob * 64 + t) * 1024 + dir * 512 + ou] = f2bf(hmix * mval);
      Hbf[(pp ^ 1) * 16384 + ob * 512 + ou] = f2bf(hmix);
      if (s == 63) {
        HFIN[dir * 16384 + ob * 512 + ou] = hmix;
        HFIN[(2 + dir) * 16384 + ob * 512 + ou] = cmix;
      }
    }
    if (s < 63) { tgt += 128; gbar(cnt, tgt); }
  }
}

// ---------------------------------------------------------------------------
// Decoder megakernel (MFMA).  128 blocks, 2 barriers/step.   (unchanged)
// ---------------------------------------------------------------------------
__global__ __launch_bounds__(256) void mega_dec_kernel(
    const float* __restrict__ HFIN, const float* __restrict__ W_h,
    const float* __restrict__ b_h, const float* __restrict__ W_c,
    const float* __restrict__ b_c, const float* __restrict__ XD,
    const float* __restrict__ Wih_d, const float* __restrict__ Whh_d,
    const float* __restrict__ EFG, const unsigned short* __restrict__ ENCO,
    const float* __restrict__ mask, float* __restrict__ DECH,
    float* __restrict__ DECC, unsigned short* __restrict__ PRE0,
    unsigned short* __restrict__ ACAT, unsigned* bar) {
  const int bi = blockIdx.x;
  const int tid = threadIdx.x;
  const int u0 = bi * 4;

  __shared__ union {
    struct {
      unsigned short wga[16 * 1544];  // gates A bf16, k-order [h|ctx]
      unsigned short xb[32 * 1544];   // gates B bf16 (= ACAT row layout)
      float hcl[1024];
      float gl[16][33];
      float scl[64];
      float al[64];
    } s;
    struct { float xl[32][132]; float wi[8][132]; } ini;
  } U;

  // ---- init: dec_h = relu([hf,hb]@W_h^T+b_h); dec_c likewise (fp32) ----
  {
    const int mat = bi >> 6, j0i = (bi & 63) * 8;
    const int jj = tid >> 5, b = tid & 31;
    const int sr = tid >> 5, sc = (tid & 31) * 4;
    const float* Wm = mat ? W_c : W_h;
    const float* bias = mat ? b_c : b_h;
    const float* x0 = HFIN + (size_t)(mat ? 2 : 0) * 16384;
    const float* x1 = HFIN + (size_t)(mat ? 3 : 1) * 16384;
    float acc = 0.f;
    for (int kc = 0; kc < 1024; kc += 128) {
#pragma unroll
      for (int i = 0; i < 4; ++i) {
        int r = sr + i * 8;
        const float* src = (kc < 512) ? (x0 + r * 512 + kc + sc)
                                      : (x1 + r * 512 + (kc - 512) + sc);
        *(float4*)&U.ini.xl[r][sc] = *(const float4*)src;
      }
      *(float4*)&U.ini.wi[sr][sc] = *(const float4*)(Wm + (size_t)(j0i + sr) * 1024 + kc + sc);
      __syncthreads();
#pragma unroll
      for (int k = 0; k < 128; k += 4) {
        float4 wv = *(const float4*)&U.ini.wi[jj][k];
        float4 xv = *(const float4*)&U.ini.xl[b][k];
        acc += wv.x * xv.x + wv.y * xv.y + wv.z * xv.z + wv.w * xv.w;
      }
      __syncthreads();
    }
    float v = fmaxf(acc + bias[j0i + jj], 0.f);
    if (mat == 0) {
      DECH[b * 512 + j0i + jj] = v;
      PRE0[(size_t)b * 1536 + j0i + jj] = f2bf(v);
    } else {
      DECC[b * 512 + j0i + jj] = v;
    }
  }
  unsigned tgt = 128;
  gbar(bar, tgt);

  // ---- preconvert gates A to bf16 LDS (after init: union switch) ----
#pragma unroll
  for (int i = 0; i < 24; ++i) {
    int idx = tid + i * 256;              // 16 rows x 384 float4-cols
    int r = idx / 384, c4 = idx - (idx / 384) * 384;
    int wrow = (r >> 2) * 512 + u0 + (r & 3);
    int c = c4 * 4;
    float4 v;
    if (c < 512) v = *(const float4*)(Whh_d + (size_t)wrow * 512 + c);
    else         v = *(const float4*)(Wih_d + (size_t)wrow * 1280 + 256 + (c - 512));
    *(uint2*)(U.s.wga + r * 1544 + c) = make_uint2(pack_bf2(v.x, v.y), pack_bf2(v.z, v.w));
  }

  const int ob = tid & 31, ouo = (tid >> 5) & 3, ou = u0 + ouo;
  float h_reg = 0.f, c_reg = 0.f;
  if (tid < 128) { h_reg = DECH[ob * 512 + ou]; c_reg = DECC[ob * 512 + ou]; }

  const int w = tid >> 6, lane = tid & 63;
  const int l15 = lane & 15, l4 = lane >> 4;

  for (int t = 0; t < 31; ++t) {
    // owner XD prefetch
    float xg0 = 0, xg1 = 0, xg2 = 0, xg3 = 0;
    if (tid < 128) {
      const float* xp = XD + ((size_t)ob * 31 + t) * 2048 + ou;
      xg0 = xp[0]; xg1 = xp[512]; xg2 = xp[1024]; xg3 = xp[1536];
    }
    // stage B = [h|ctx] bf16 rows (32 x 1536 shorts, 192 uint4/row)
#pragma unroll
    for (int i = 0; i < 24; ++i) {
      int idx = tid + i * 256;
      int r = idx / 192, c16 = idx - (idx / 192) * 192;
      const unsigned short* src = (t == 0)
          ? (PRE0 + (size_t)r * 1536 + c16 * 8)
          : (ACAT + ((size_t)r * 31 + (t - 1)) * 1536 + c16 * 8);
      uint4 v = *(const uint4*)src;
      *(uint4*)(U.s.xb + r * 1544 + c16 * 8) = v;
    }
    __syncthreads();
    if (w < 2) {
      f4_t ae = {0.f, 0.f, 0.f, 0.f}, ao = {0.f, 0.f, 0.f, 0.f};
#pragma unroll
      for (int kk = 0; kk < 48; kk += 2) {
        bfrag_t a0 = *(const bfrag_t*)(U.s.wga + l15 * 1544 + kk * 32 + l4 * 8);
        bfrag_t b0 = *(const bfrag_t*)(U.s.xb + (w * 16 + l15) * 1544 + kk * 32 + l4 * 8);
        bfrag_t a1 = *(const bfrag_t*)(U.s.wga + l15 * 1544 + (kk + 1) * 32 + l4 * 8);
        bfrag_t b1 = *(const bfrag_t*)(U.s.xb + (w * 16 + l15) * 1544 + (kk + 1) * 32 + l4 * 8);
        ae = __builtin_amdgcn_mfma_f32_16x16x32_bf16(a0, b0, ae, 0, 0, 0);
        ao = __builtin_amdgcn_mfma_f32_16x16x32_bf16(a1, b1, ao, 0, 0, 0);
      }
#pragma unroll
      for (int r = 0; r < 4; ++r)
        U.s.gl[l4 * 4 + r][w * 16 + l15] = ae[r] + ao[r];
    }
    __syncthreads();
    if (tid < 128) {
      float gi = U.s.gl[ouo][ob] + xg0;
      float gf = U.s.gl[4 + ouo][ob] + xg1;
      float gg = U.s.gl[8 + ouo][ob] + xg2;
      float go = U.s.gl[12 + ouo][ob] + xg3;
      float cn = sigm(gf) * c_reg + sigm(gi) * tanhf(gg);
      float hn = sigm(go) * tanhf(cn);
      h_reg = hn; c_reg = cn;
      DECH[ob * 512 + ou] = hn;
      DECC[ob * 512 + ou] = cn;
      ACAT[((size_t)ob * 31 + t) * 1536 + ou] = f2bf(hn);
    }
    tgt += 128;
    gbar(bar, tgt);
    // ---- attention: blocks 0..31, one batch each ----
    if (bi < 32) {
      const int b = bi;
      {
        int c = tid * 4;
        float4 v = (c < 512) ? *(const float4*)(DECH + b * 512 + c)
                             : *(const float4*)(DECC + b * 512 + (c - 512));
        *(float4*)&U.s.hcl[c] = v;
      }
      __syncthreads();
      {
        const int sidx = tid >> 2, part = tid & 3;
        const float* eg = EFG + ((size_t)b * 64 + sidx) * 1152 + part * 256;
        float acc = 0.f;
        for (int k = 0; k < 256; k += 4) {
          float4 e = *(const float4*)(eg + k);
          float4 d = *(const float4*)(&U.s.hcl[part * 256 + k]);
          acc += e.x * d.x + e.y * d.y + e.z * d.z + e.w * d.w;
        }
        acc += __shfl_xor(acc, 1);
        acc += __shfl_xor(acc, 2);
        if (part == 0)
          U.s.scl[sidx] = acc + EFG[((size_t)b * 64 + sidx) * 1152 + 1024];
      }
      __syncthreads();
      if (tid < 64) {
        float v = U.s.scl[tid];
        float mx = v;
#pragma unroll
        for (int o = 32; o >= 1; o >>= 1) mx = fmaxf(mx, __shfl_xor(mx, o));
        float e = expf(v - mx) * mask[b * 64 + tid];
        float sm = e;
#pragma unroll
        for (int o = 32; o >= 1; o >>= 1) sm += __shfl_xor(sm, o);
        U.s.al[tid] = e / sm;
      }
      __syncthreads();
      float c0 = 0.f, c1 = 0.f, c2 = 0.f, c3 = 0.f;
      for (int tp = 0; tp < 64; ++tp) {
        float a = U.s.al[tp];
        const unsigned short* eo = ENCO + ((size_t)b * 64 + tp) * 1024 + tid;
        c0 += a * bf2f(eo[0]);
        c1 += a * bf2f(eo[256]);
        c2 += a * bf2f(eo[512]);
        c3 += a * bf2f(eo[768]);
      }
      unsigned short* ap = ACAT + ((size_t)b * 31 + t) * 1536 + 512;
      ap[tid] = f2bf(c0); ap[tid + 256] = f2bf(c1);
      ap[tid + 512] = f2bf(c2); ap[tid + 768] = f2bf(c3);
    }
    if (t < 30) { tgt += 128; gbar(bar, tgt); }
  }
}

// ============================================================================
extern "C" void kernel_launch(void* const* d_in, const int* in_sizes, int n_in,
                              void* d_out, int out_size, void* d_ws, size_t ws_size,
                              hipStream_t stream) {
  const int*   enc_texts = (const int*)  d_in[0];
  const float* enc_mask  = (const float*)d_in[1];
  const int*   dec_texts = (const int*)  d_in[2];
  const float* enc_emb   = (const float*)d_in[3];
  const float* dec_emb   = (const float*)d_in[4];
  const float* Wih_f = (const float*)d_in[5];
  const float* Whh_f = (const float*)d_in[6];
  const float* b_f   = (const float*)d_in[7];
  const float* Wih_b = (const float*)d_in[8];
  const float* Whh_b = (const float*)d_in[9];
  const float* b_b   = (const float*)d_in[10];
  const float* Wih_d = (const float*)d_in[11];
  const float* Whh_d = (const float*)d_in[12];
  const float* b_d   = (const float*)d_in[13];
  const float* W_h   = (const float*)d_in[14];
  const float* b_h   = (const float*)d_in[15];
  const float* W_c   = (const float*)d_in[16];
  const float* b_c   = (const float*)d_in[17];
  const float* W_df  = (const float*)d_in[18];
  const float* b_df  = (const float*)d_in[19];
  const float* W_ef  = (const float*)d_in[20];
  const float* b_ef  = (const float*)d_in[21];
  const float* W_out = (const float*)d_in[22];
  const float* b_out = (const float*)d_in[23];
  float* out = (float*)d_out;

  char* ws = (char*)d_ws;
  size_t off = 0;
  auto alloc = [&](size_t bytes) {
    char* p = ws + off;
    off += (bytes + 255) & ~(size_t)255;
    return p;
  };
  // --- zero-init group ---
  unsigned short* HBF  = (unsigned short*)alloc((size_t)2 * 2 * 16384 * 2);  // [dir][pp][32*512]
  float* DECH = (float*)alloc((size_t)16384 * 4);
  float* DECC = (float*)alloc((size_t)16384 * 4);
  unsigned short* PRE0 = (unsigned short*)alloc((size_t)32 * 1536 * 2);
  unsigned short* ACAT = (unsigned short*)alloc((size_t)1024 * 1536 * 2);
  unsigned* bar = (unsigned*)alloc(1024);  // counters at +0, +32, +64 (uints)
  size_t zbytes = off;
  // --- rest ---
  float* XF = (float*)alloc((size_t)2048 * 2048 * 4);
  float* XB = (float*)alloc((size_t)2048 * 2048 * 4);
  float* XD = (float*)alloc((size_t)1024 * 2048 * 4);
  unsigned short* EFb  = (unsigned short*)alloc((size_t)2048 * 1024 * 2);
  unsigned short* ENCO = (unsigned short*)alloc((size_t)2048 * 1024 * 2);
  unsigned short* EMBB = (unsigned short*)alloc((size_t)2048 * 256 * 2);
  unsigned short* DEMB = (unsigned short*)alloc((size_t)1024 * 256 * 2);
  float* HFIN = (float*)alloc((size_t)4 * 16384 * 4);
  // aliases (lifetimes: written after mega_enc consumed XF/XB)
  float* EFG = XF;   // 2048 x 1152 fp32
  float* WT  = XB;   // 1152 x 1024 fp32

  hipMemsetAsync(d_ws, 0, zbytes, stream);

  gather_enc_kernel<<<2048, 64, 0, stream>>>(enc_texts, enc_emb, EMBB);
  gather_dec_kernel<<<1024, 64, 0, stream>>>(dec_texts, dec_emb, DEMB);

  dim3 blk(256);
  gemm_bt_kernel<<<256, blk, 0, stream>>>(EMBB, 256, Wih_f, 256, 0, b_f, XF, 2048, 2048, 256, 16, 0, 0);
  gemm_bt_kernel<<<256, blk, 0, stream>>>(EMBB, 256, Wih_b, 256, 0, b_b, XB, 2048, 2048, 256, 16, 0, 0);
  gemm_bt_kernel<<<128, blk, 0, stream>>>(DEMB, 256, Wih_d, 1280, 0, b_d, XD, 2048, 1024, 256, 8, 0, 0);

  mega_enc_kernel<<<256, blk, 0, stream>>>(XF, XB, Whh_f, Whh_b, enc_mask, HBF, ENCO, HFIN, bar);

  wdf_t_kernel<<<1025, blk, 0, stream>>>(W_df, b_df, WT);
  gemm_bt_kernel<<<128, blk, 0, stream>>>(ENCO, 1024, W_ef, 1024, 0, b_ef, EFb, 1024, 2048, 1024, 16, 0, 1);
  gemm_bt_kernel<<<144, blk, 0, stream>>>(EFb, 1024, WT, 1024, 0, nullptr, EFG, 1152, 2048, 1024, 16, 0, 0);

  mega_dec_kernel<<<128, blk, 0, stream>>>(HFIN, W_h, b_h, W_c, b_c, XD, Wih_d, Whh_d,
                                           EFG, ENCO, enc_mask, DECH, DECC, PRE0, ACAT, bar + 64);

  // logits = [h, ctx] @ W_out^T + b_out  (97.5 GFLOP, XCD-swizzled)
  gemm_bt_kernel<<<2000, blk, 0, stream>>>(ACAT, 1536, W_out, 1536, 0, b_out, out, 32000, 992, 1536, 8, 1, 0);
}

// Round 6
// 1455.951 us; speedup vs baseline: 3.7053x; 1.6883x over previous
//
#include <hip/hip_runtime.h>
#include <hip/hip_bf16.h>

// ============================================================================
// seq2seq + attention on MI355X.  B=32, Te=64, Td=32 (31 steps), E=256, H=512,
// V=32000.  Round 6: fence-free grid barrier + device-coherent (sc0 sc1)
// data path for all intra-kernel cross-block traffic.
//   - barrier: __syncthreads (drains vmcnt -> sc1 stores at LLC) + relaxed
//     far-atomic add to 8 distributed counter lines + wave-parallel poll.
//     No buffer_wbl2 / buffer_inv per interval (that was the 18us/interval).
//   - producers of HBF/DECH/DECC/PRE0/ACAT use global_store_* sc0 sc1;
//     consumers use global_load_* sc0 sc1.  Read-only data (W, EFG, XD, X,
//     ENCO-from-prev-kernel) keeps normal cached loads and now stays
//     L2-resident since nothing invalidates L2 anymore.
// ============================================================================

typedef __attribute__((ext_vector_type(8))) short bfrag_t;
typedef __attribute__((ext_vector_type(4))) float f4_t;

static __device__ __forceinline__ float bf2f(unsigned short u) {
  union { float f; unsigned int i; } v; v.i = ((unsigned int)u) << 16; return v.f;
}
static __device__ __forceinline__ unsigned short f2bf(float f) {
  union { float f; unsigned int i; } v; v.f = f;
  unsigned int r = v.i + 0x7FFFu + ((v.i >> 16) & 1u);  // RNE
  return (unsigned short)(r >> 16);
}
static __device__ __forceinline__ unsigned int pack_bf2(float lo, float hi) {
  __hip_bfloat162 h2 = __float22bfloat162_rn(make_float2(lo, hi));
  union { __hip_bfloat162 h; unsigned int u; } cv; cv.h = h2;
  return cv.u;
}
static __device__ __forceinline__ float sigm(float x) { return 1.f / (1.f + expf(-x)); }

#define GLDS16(g, l)                                                        \
  __builtin_amdgcn_global_load_lds(                                         \
      (const __attribute__((address_space(1))) void*)(g),                   \
      (__attribute__((address_space(3))) void*)(l), 16, 0, 0)

// ---- device-coherent (agent-scope) access helpers: bypass L2 via sc0 sc1 ----
static __device__ __forceinline__ void st_f32_coh(float* p, float v) {
  asm volatile("global_store_dword %0, %1, off sc0 sc1" :: "v"(p), "v"(v) : "memory");
}
static __device__ __forceinline__ void st_u16_coh(unsigned short* p, unsigned short x) {
  asm volatile("global_store_short %0, %1, off sc0 sc1" :: "v"(p), "v"((unsigned)x) : "memory");
}
static __device__ __forceinline__ float ld_f32_coh(const float* p) {
  float v;
  asm volatile("global_load_dword %0, %1, off sc0 sc1\n\ts_waitcnt vmcnt(0)"
               : "=v"(v) : "v"(p) : "memory");
  return v;
}

// ---------------------------------------------------------------------------
// Fence-free grid barrier.  8 counter lines (128 B apart) per barrier group;
// monotonic targets.  Entry __syncthreads drains each wave's vmcnt, which
// makes prior sc1 stores globally visible; polls are relaxed far-atomic
// loads (no L2 invalidation).  Wave 0 polls all 8 counters in parallel.
// ---------------------------------------------------------------------------
static __device__ __forceinline__ void gbar8(unsigned* base, unsigned target) {
  __syncthreads();
  if (threadIdx.x < 64) {
    if (threadIdx.x == 0)
      __hip_atomic_fetch_add(base + (blockIdx.x & 7) * 32, 1u,
                             __ATOMIC_RELAXED, __HIP_MEMORY_SCOPE_AGENT);
    unsigned sum;
    do {
      unsigned v = 0;
      if (threadIdx.x < 8)
        v = __hip_atomic_load(base + threadIdx.x * 32,
                              __ATOMIC_RELAXED, __HIP_MEMORY_SCOPE_AGENT);
      v += __shfl_xor(v, 1);
      v += __shfl_xor(v, 2);
      v += __shfl_xor(v, 4);
      sum = __shfl(v, 0);
      if (sum < target) __builtin_amdgcn_s_sleep(2);
    } while (sum < target);
  }
  __syncthreads();
}

// ---------------------------------------------------------------------------
// C = A(bf16, MxK, lda) @ B(fp32 NxldB rows, +bcol0)^T + bias.   (unchanged)
// ---------------------------------------------------------------------------
__global__ __launch_bounds__(256) void gemm_bt_kernel(
    const unsigned short* __restrict__ A, int lda,
    const float* __restrict__ B, int ldb, int bcol0,
    const float* __restrict__ bias, void* __restrict__ Cv, int ldc,
    int Mvalid, int K, int Mt, int swz, int obf) {
  __shared__ unsigned short As[128 * 32];
  __shared__ unsigned short Bs[128 * 32];
  int id = blockIdx.x;
  if (swz) { int x = id & 7; id = x * ((int)gridDim.x >> 3) + (id >> 3); }
  const int mb = id % Mt, nb = id / Mt;
  const int m0 = mb * 128, n0 = nb * 128;
  const int tid = threadIdx.x;
  const int w = tid >> 6, lane = tid & 63;
  const int wr = (w >> 1) * 64, wc = (w & 1) * 64;
  const int l15 = lane & 15, l4 = lane >> 4;

  const int arow = w * 16 + (lane >> 2);
  const int acol = (lane & 3) * 8;
  const unsigned short* Ag = A + (size_t)(m0 + arow) * lda + acol;

  const int brow = tid >> 1;
  const int bcol = (tid & 1) * 16;
  const float* Bg = B + (size_t)(n0 + brow) * ldb + bcol0 + bcol;
  unsigned short* Bsw = Bs + brow * 32 + bcol;

  f4_t acc[4][4];
#pragma unroll
  for (int i = 0; i < 4; ++i)
#pragma unroll
    for (int j = 0; j < 4; ++j) {
      acc[i][j].x = 0.f; acc[i][j].y = 0.f; acc[i][j].z = 0.f; acc[i][j].w = 0.f;
    }

  for (int kt = 0; kt < K; kt += 32) {
    GLDS16(Ag + kt, As + w * 512);
    GLDS16(Ag + (size_t)64 * lda + kt, As + (4 + w) * 512);
    float4 q0 = *(const float4*)(Bg + kt);
    float4 q1 = *(const float4*)(Bg + kt + 4);
    float4 q2 = *(const float4*)(Bg + kt + 8);
    float4 q3 = *(const float4*)(Bg + kt + 12);
    union { unsigned int u[8]; uint4 q[2]; } pk;
    pk.u[0] = pack_bf2(q0.x, q0.y); pk.u[1] = pack_bf2(q0.z, q0.w);
    pk.u[2] = pack_bf2(q1.x, q1.y); pk.u[3] = pack_bf2(q1.z, q1.w);
    pk.u[4] = pack_bf2(q2.x, q2.y); pk.u[5] = pack_bf2(q2.z, q2.w);
    pk.u[6] = pack_bf2(q3.x, q3.y); pk.u[7] = pack_bf2(q3.z, q3.w);
    *(uint4*)(Bsw) = pk.q[0];
    *(uint4*)(Bsw + 8) = pk.q[1];
    __syncthreads();
    bfrag_t af[4], bfv[4];
#pragma unroll
    for (int m = 0; m < 4; ++m)
      af[m] = *(const bfrag_t*)(As + (wr + m * 16 + l15) * 32 + l4 * 8);
#pragma unroll
    for (int n = 0; n < 4; ++n)
      bfv[n] = *(const bfrag_t*)(Bs + (wc + n * 16 + l15) * 32 + l4 * 8);
#pragma unroll
    for (int m = 0; m < 4; ++m)
#pragma unroll
      for (int n = 0; n < 4; ++n)
        acc[m][n] = __builtin_amdgcn_mfma_f32_16x16x32_bf16(af[m], bfv[n], acc[m][n], 0, 0, 0);
    __syncthreads();
  }

  const int crb = l4 * 4;
  float* Cf = (float*)Cv;
  unsigned short* Ch = (unsigned short*)Cv;
#pragma unroll
  for (int m = 0; m < 4; ++m)
#pragma unroll
    for (int n = 0; n < 4; ++n)
#pragma unroll
      for (int r = 0; r < 4; ++r) {
        int gr = m0 + wr + m * 16 + crb + r;
        if (gr < Mvalid) {
          int gc = n0 + wc + n * 16 + l15;
          float v = acc[m][n][r] + (bias ? bias[gc] : 0.f);
          if (obf) Ch[(size_t)gr * ldc + gc] = f2bf(v);
          else     Cf[(size_t)gr * ldc + gc] = v;
        }
      }
}

// ---------------------------------------------------------------------------
// Embedding gathers -> bf16   (unchanged)
// ---------------------------------------------------------------------------
__global__ void gather_enc_kernel(const int* __restrict__ texts,
                                  const float* __restrict__ table,
                                  unsigned short* __restrict__ out) {
  const int row = blockIdx.x;
  const int tok = texts[row];
  const float4 v = *(const float4*)(table + (size_t)tok * 256 + threadIdx.x * 4);
  unsigned short* o = out + (size_t)row * 256 + threadIdx.x * 4;
  o[0] = f2bf(v.x); o[1] = f2bf(v.y); o[2] = f2bf(v.z); o[3] = f2bf(v.w);
}

__global__ void gather_dec_kernel(const int* __restrict__ texts,
                                  const float* __restrict__ table,
                                  unsigned short* __restrict__ out) {
  const int row = blockIdx.x;
  unsigned short* o = out + (size_t)row * 256 + threadIdx.x * 4;
  if (row >= 992) { o[0] = 0; o[1] = 0; o[2] = 0; o[3] = 0; return; }
  const int b = row / 31, t2 = row - b * 31;
  const int tok = texts[b * 32 + t2];
  const float4 v = *(const float4*)(table + (size_t)tok * 256 + threadIdx.x * 4);
  o[0] = f2bf(v.x); o[1] = f2bf(v.y); o[2] = f2bf(v.z); o[3] = f2bf(v.w);
}

// ---------------------------------------------------------------------------
// W_dfT[n][j] = W_df[j][n] (1024x1024), row 1024 = b_df.   (unchanged)
// ---------------------------------------------------------------------------
__global__ __launch_bounds__(256) void wdf_t_kernel(
    const float* __restrict__ W_df, const float* __restrict__ b_df,
    float* __restrict__ WT) {
  const int bid = blockIdx.x;
  if (bid < 1024) {
    __shared__ float tl[32][33];
    const int tx = (bid & 31) * 32, ty = (bid >> 5) * 32;
    const int r = threadIdx.x >> 5, c = threadIdx.x & 31;
#pragma unroll
    for (int i = 0; i < 4; ++i)
      tl[r + i * 8][c] = W_df[(size_t)(ty + r + i * 8) * 1024 + tx + c];
    __syncthreads();
#pragma unroll
    for (int i = 0; i < 4; ++i)
      WT[(size_t)(tx + r + i * 8) * 1024 + ty + c] = tl[c][r + i * 8];
  } else {
    for (int i = threadIdx.x; i < 1024; i += 256)
      WT[(size_t)1024 * 1024 + i] = b_df[i];
  }
}

// ---------------------------------------------------------------------------
// Encoder megakernel (MFMA).  256 blocks: dir=bi>>7, 4 units each; 64 steps.
// Cross-block h exchange (HBF) via coherent sc1 stores/loads.
// ---------------------------------------------------------------------------
__global__ __launch_bounds__(256) void mega_enc_kernel(
    const float* __restrict__ XF, const float* __restrict__ XB,
    const float* __restrict__ Whh_f, const float* __restrict__ Whh_b,
    const float* __restrict__ mask,
    unsigned short* __restrict__ HBF,   // [dir][pp][32*512] bf16
    unsigned short* __restrict__ ENCO, float* __restrict__ HFIN,
    unsigned* bar) {
  const int bi = blockIdx.x;
  const int dir = bi >> 7;
  const int u0 = (bi & 127) * 4;
  const int tid = threadIdx.x;
  const float* X = dir ? XB : XF;
  const float* W = dir ? Whh_b : Whh_f;
  unsigned short* Hbf = HBF + dir * 32768;
  unsigned* cnt = bar + dir * 256;   // 1 KiB group per direction

  __shared__ unsigned short WA[16 * 520];   // row j=(gate*4+ul), padded stride
  __shared__ unsigned short HB[32 * 520];   // row = batch
  __shared__ float Gl[16][33];

  // one-time: Whh slice rows -> bf16 LDS.  row j -> Whh[(j>>2)*512+u0+(j&3)]
#pragma unroll
  for (int i = 0; i < 8; ++i) {
    int idx = tid + i * 256;               // 16 rows x 128 float4-cols
    int r = idx >> 7, c4 = idx & 127;
    const float4 v = *(const float4*)(W + (size_t)((r >> 2) * 512 + u0 + (r & 3)) * 512 + c4 * 4);
    *(uint2*)(WA + r * 520 + c4 * 4) = make_uint2(pack_bf2(v.x, v.y), pack_bf2(v.z, v.w));
  }
  __syncthreads();

  const int w = tid >> 6, lane = tid & 63;
  const int l15 = lane & 15, l4 = lane >> 4;

  bfrag_t afr[16];
  if (w < 2) {
#pragma unroll
    for (int kk = 0; kk < 16; ++kk)
      afr[kk] = *(const bfrag_t*)(WA + l15 * 520 + kk * 32 + l4 * 8);
  }

  const int ob = tid & 31, ouo = (tid >> 5) & 3;
  const int ou = u0 + ouo;
  float h_reg = 0.f, c_reg = 0.f;

  unsigned tgt = 0;
  for (int s = 0; s < 64; ++s) {
    const int t = dir ? (63 - s) : s;
    const int pp = s & 1;
    // owner prefetch: X gates + mask (normal cached loads; read-only data)
    float xg0 = 0, xg1 = 0, xg2 = 0, xg3 = 0, mval = 0;
    if (tid < 128) {
      const float* xp = X + ((size_t)ob * 64 + t) * 2048 + ou;
      xg0 = xp[0]; xg1 = xp[512]; xg2 = xp[1024]; xg3 = xp[1536];
      mval = mask[ob * 64 + t];
    }
    // stage h (bf16, 32 rows x 64 uint4/row) via coherent loads
    const unsigned short* hsrc = Hbf + pp * 16384;
    uint4 tmp[8];
#pragma unroll
    for (int i = 0; i < 8; ++i) {
      int idx = tid + i * 256;
      int r = idx >> 6, c = idx & 63;
      asm volatile("global_load_dwordx4 %0, %1, off sc0 sc1"
                   : "=v"(tmp[i]) : "v"(hsrc + r * 512 + c * 8));
    }
    asm volatile("s_waitcnt vmcnt(0)" ::: "memory");
#pragma unroll
    for (int i = 0; i < 8; ++i) {
      int idx = tid + i * 256;
      int r = idx >> 6, c = idx & 63;
      *(uint4*)(HB + r * 520 + c * 8) = tmp[i];
    }
    __syncthreads();
    if (w < 2) {
      f4_t ae = {0.f, 0.f, 0.f, 0.f}, ao = {0.f, 0.f, 0.f, 0.f};
#pragma unroll
      for (int kk = 0; kk < 16; kk += 2) {
        bfrag_t b0 = *(const bfrag_t*)(HB + (w * 16 + l15) * 520 + kk * 32 + l4 * 8);
        bfrag_t b1 = *(const bfrag_t*)(HB + (w * 16 + l15) * 520 + (kk + 1) * 32 + l4 * 8);
        ae = __builtin_amdgcn_mfma_f32_16x16x32_bf16(afr[kk], b0, ae, 0, 0, 0);
        ao = __builtin_amdgcn_mfma_f32_16x16x32_bf16(afr[kk + 1], b1, ao, 0, 0, 0);
      }
#pragma unroll
      for (int r = 0; r < 4; ++r)
        Gl[l4 * 4 + r][w * 16 + l15] = ae[r] + ao[r];
    }
    __syncthreads();
    if (tid < 128) {
      float gi = Gl[ouo][ob] + xg0;
      float gf = Gl[4 + ouo][ob] + xg1;
      float gg = Gl[8 + ouo][ob] + xg2;
      float go = Gl[12 + ouo][ob] + xg3;
      float cn = sigm(gf) * c_reg + sigm(gi) * tanhf(gg);
      float hn = sigm(go) * tanhf(cn);
      float hmix = mval * hn + (1.f - mval) * h_reg;
      float cmix = mval * cn + (1.f - mval) * c_reg;
      h_reg = hmix; c_reg = cmix;
      ENCO[((size_t)ob * 64 + t) * 1024 + dir * 512 + ou] = f2bf(hmix * mval);  // cross-kernel
      st_u16_coh(Hbf + (pp ^ 1) * 16384 + ob * 512 + ou, f2bf(hmix));           // intra-kernel
      if (s == 63) {
        HFIN[dir * 16384 + ob * 512 + ou] = hmix;          // cross-kernel
        HFIN[(2 + dir) * 16384 + ob * 512 + ou] = cmix;
      }
    }
    if (s < 63) { tgt += 128; gbar8(cnt, tgt); }
  }
}

// ---------------------------------------------------------------------------
// Decoder megakernel (MFMA).  128 blocks, 2 barriers/step.
// All intra-kernel cross-block data via coherent sc1 stores/loads.
// ---------------------------------------------------------------------------
__global__ __launch_bounds__(256) void mega_dec_kernel(
    const float* __restrict__ HFIN, const float* __restrict__ W_h,
    const float* __restrict__ b_h, const float* __restrict__ W_c,
    const float* __restrict__ b_c, const float* __restrict__ XD,
    const float* __restrict__ Wih_d, const float* __restrict__ Whh_d,
    const float* __restrict__ EFG, const unsigned short* __restrict__ ENCO,
    const float* __restrict__ mask, float* __restrict__ DECH,
    float* __restrict__ DECC, unsigned short* __restrict__ PRE0,
    unsigned short* __restrict__ ACAT, unsigned* bar) {
  const int bi = blockIdx.x;
  const int tid = threadIdx.x;
  const int u0 = bi * 4;

  __shared__ union {
    struct {
      unsigned short wga[16 * 1544];  // gates A bf16, k-order [h|ctx]
      unsigned short xb[32 * 1544];   // gates B bf16 (= ACAT row layout)
      float hcl[1024];
      float gl[16][33];
      float scl[64];
      float al[64];
    } s;
    struct { float xl[32][132]; float wi[8][132]; } ini;
  } U;

  // ---- init: dec_h = relu([hf,hb]@W_h^T+b_h); dec_c likewise (fp32) ----
  {
    const int mat = bi >> 6, j0i = (bi & 63) * 8;
    const int jj = tid >> 5, b = tid & 31;
    const int sr = tid >> 5, sc = (tid & 31) * 4;
    const float* Wm = mat ? W_c : W_h;
    const float* bias = mat ? b_c : b_h;
    const float* x0 = HFIN + (size_t)(mat ? 2 : 0) * 16384;
    const float* x1 = HFIN + (size_t)(mat ? 3 : 1) * 16384;
    float acc = 0.f;
    for (int kc = 0; kc < 1024; kc += 128) {
#pragma unroll
      for (int i = 0; i < 4; ++i) {
        int r = sr + i * 8;
        const float* src = (kc < 512) ? (x0 + r * 512 + kc + sc)
                                      : (x1 + r * 512 + (kc - 512) + sc);
        *(float4*)&U.ini.xl[r][sc] = *(const float4*)src;
      }
      *(float4*)&U.ini.wi[sr][sc] = *(const float4*)(Wm + (size_t)(j0i + sr) * 1024 + kc + sc);
      __syncthreads();
#pragma unroll
      for (int k = 0; k < 128; k += 4) {
        float4 wv = *(const float4*)&U.ini.wi[jj][k];
        float4 xv = *(const float4*)&U.ini.xl[b][k];
        acc += wv.x * xv.x + wv.y * xv.y + wv.z * xv.z + wv.w * xv.w;
      }
      __syncthreads();
    }
    float v = fmaxf(acc + bias[j0i + jj], 0.f);
    if (mat == 0) {
      st_f32_coh(DECH + b * 512 + j0i + jj, v);
      st_u16_coh(PRE0 + (size_t)b * 1536 + j0i + jj, f2bf(v));
    } else {
      st_f32_coh(DECC + b * 512 + j0i + jj, v);
    }
  }
  unsigned tgt = 128;
  gbar8(bar, tgt);

  // ---- preconvert gates A to bf16 LDS (after init: union switch) ----
#pragma unroll
  for (int i = 0; i < 24; ++i) {
    int idx = tid + i * 256;              // 16 rows x 384 float4-cols
    int r = idx / 384, c4 = idx - (idx / 384) * 384;
    int wrow = (r >> 2) * 512 + u0 + (r & 3);
    int c = c4 * 4;
    float4 v;
    if (c < 512) v = *(const float4*)(Whh_d + (size_t)wrow * 512 + c);
    else         v = *(const float4*)(Wih_d + (size_t)wrow * 1280 + 256 + (c - 512));
    *(uint2*)(U.s.wga + r * 1544 + c) = make_uint2(pack_bf2(v.x, v.y), pack_bf2(v.z, v.w));
  }

  const int ob = tid & 31, ouo = (tid >> 5) & 3, ou = u0 + ouo;
  float h_reg = 0.f, c_reg = 0.f;
  if (tid < 128) {
    h_reg = ld_f32_coh(DECH + ob * 512 + ou);
    c_reg = ld_f32_coh(DECC + ob * 512 + ou);
  }

  const int w = tid >> 6, lane = tid & 63;
  const int l15 = lane & 15, l4 = lane >> 4;

  for (int t = 0; t < 31; ++t) {
    // owner XD prefetch (read-only, normal loads)
    float xg0 = 0, xg1 = 0, xg2 = 0, xg3 = 0;
    if (tid < 128) {
      const float* xp = XD + ((size_t)ob * 31 + t) * 2048 + ou;
      xg0 = xp[0]; xg1 = xp[512]; xg2 = xp[1024]; xg3 = xp[1536];
    }
    // stage B = [h|ctx] bf16 rows (32 x 192 uint4) via coherent loads
#pragma unroll
    for (int half = 0; half < 2; ++half) {
      uint4 tmp[12];
#pragma unroll
      for (int i = 0; i < 12; ++i) {
        int idx = tid + (half * 12 + i) * 256;
        int r = idx / 192, c16 = idx - (idx / 192) * 192;
        const unsigned short* src = (t == 0)
            ? (PRE0 + (size_t)r * 1536 + c16 * 8)
            : (ACAT + ((size_t)r * 31 + (t - 1)) * 1536 + c16 * 8);
        asm volatile("global_load_dwordx4 %0, %1, off sc0 sc1"
                     : "=v"(tmp[i]) : "v"(src));
      }
      asm volatile("s_waitcnt vmcnt(0)" ::: "memory");
#pragma unroll
      for (int i = 0; i < 12; ++i) {
        int idx = tid + (half * 12 + i) * 256;
        int r = idx / 192, c16 = idx - (idx / 192) * 192;
        *(uint4*)(U.s.xb + r * 1544 + c16 * 8) = tmp[i];
      }
    }
    __syncthreads();
    if (w < 2) {
      f4_t ae = {0.f, 0.f, 0.f, 0.f}, ao = {0.f, 0.f, 0.f, 0.f};
#pragma unroll
      for (int kk = 0; kk < 48; kk += 2) {
        bfrag_t a0 = *(const bfrag_t*)(U.s.wga + l15 * 1544 + kk * 32 + l4 * 8);
        bfrag_t b0 = *(const bfrag_t*)(U.s.xb + (w * 16 + l15) * 1544 + kk * 32 + l4 * 8);
        bfrag_t a1 = *(const bfrag_t*)(U.s.wga + l15 * 1544 + (kk + 1) * 32 + l4 * 8);
        bfrag_t b1 = *(const bfrag_t*)(U.s.xb + (w * 16 + l15) * 1544 + (kk + 1) * 32 + l4 * 8);
        ae = __builtin_amdgcn_mfma_f32_16x16x32_bf16(a0, b0, ae, 0, 0, 0);
        ao = __builtin_amdgcn_mfma_f32_16x16x32_bf16(a1, b1, ao, 0, 0, 0);
      }
#pragma unroll
      for (int r = 0; r < 4; ++r)
        U.s.gl[l4 * 4 + r][w * 16 + l15] = ae[r] + ao[r];
    }
    __syncthreads();
    if (tid < 128) {
      float gi = U.s.gl[ouo][ob] + xg0;
      float gf = U.s.gl[4 + ouo][ob] + xg1;
      float gg = U.s.gl[8 + ouo][ob] + xg2;
      float go = U.s.gl[12 + ouo][ob] + xg3;
      float cn = sigm(gf) * c_reg + sigm(gi) * tanhf(gg);
      float hn = sigm(go) * tanhf(cn);
      h_reg = hn; c_reg = cn;
      st_f32_coh(DECH + ob * 512 + ou, hn);
      st_f32_coh(DECC + ob * 512 + ou, cn);
      st_u16_coh(ACAT + ((size_t)ob * 31 + t) * 1536 + ou, f2bf(hn));
    }
    tgt += 128;
    gbar8(bar, tgt);
    // ---- attention: blocks 0..31, one batch each ----
    if (bi < 32) {
      const int b = bi;
      {
        int c = tid * 4;
        const float* hp = (c < 512) ? (DECH + b * 512 + c) : (DECC + b * 512 + (c - 512));
        uint4 hv;
        asm volatile("global_load_dwordx4 %0, %1, off sc0 sc1\n\ts_waitcnt vmcnt(0)"
                     : "=v"(hv) : "v"(hp) : "memory");
        *(uint4*)&U.s.hcl[c] = hv;
      }
      __syncthreads();
      {
        const int sidx = tid >> 2, part = tid & 3;
        const float* eg = EFG + ((size_t)b * 64 + sidx) * 1152 + part * 256;
        float acc = 0.f;
        for (int k = 0; k < 256; k += 4) {
          float4 e = *(const float4*)(eg + k);
          float4 d = *(const float4*)(&U.s.hcl[part * 256 + k]);
          acc += e.x * d.x + e.y * d.y + e.z * d.z + e.w * d.w;
        }
        acc += __shfl_xor(acc, 1);
        acc += __shfl_xor(acc, 2);
        if (part == 0)
          U.s.scl[sidx] = acc + EFG[((size_t)b * 64 + sidx) * 1152 + 1024];
      }
      __syncthreads();
      if (tid < 64) {
        float v = U.s.scl[tid];
        float mx = v;
#pragma unroll
        for (int o = 32; o >= 1; o >>= 1) mx = fmaxf(mx, __shfl_xor(mx, o));
        float e = expf(v - mx) * mask[b * 64 + tid];
        float sm = e;
#pragma unroll
        for (int o = 32; o >= 1; o >>= 1) sm += __shfl_xor(sm, o);
        U.s.al[tid] = e / sm;
      }
      __syncthreads();
      float c0 = 0.f, c1 = 0.f, c2 = 0.f, c3 = 0.f;
      for (int tp = 0; tp < 64; ++tp) {
        float a = U.s.al[tp];
        const unsigned short* eo = ENCO + ((size_t)b * 64 + tp) * 1024 + tid;
        c0 += a * bf2f(eo[0]);
        c1 += a * bf2f(eo[256]);
        c2 += a * bf2f(eo[512]);
        c3 += a * bf2f(eo[768]);
      }
      unsigned short* ap = ACAT + ((size_t)b * 31 + t) * 1536 + 512;
      st_u16_coh(ap + tid, f2bf(c0));
      st_u16_coh(ap + tid + 256, f2bf(c1));
      st_u16_coh(ap + tid + 512, f2bf(c2));
      st_u16_coh(ap + tid + 768, f2bf(c3));
    }
    if (t < 30) { tgt += 128; gbar8(bar, tgt); }
  }
}

// ============================================================================
extern "C" void kernel_launch(void* const* d_in, const int* in_sizes, int n_in,
                              void* d_out, int out_size, void* d_ws, size_t ws_size,
                              hipStream_t stream) {
  const int*   enc_texts = (const int*)  d_in[0];
  const float* enc_mask  = (const float*)d_in[1];
  const int*   dec_texts = (const int*)  d_in[2];
  const float* enc_emb   = (const float*)d_in[3];
  const float* dec_emb   = (const float*)d_in[4];
  const float* Wih_f = (const float*)d_in[5];
  const float* Whh_f = (const float*)d_in[6];
  const float* b_f   = (const float*)d_in[7];
  const float* Wih_b = (const float*)d_in[8];
  const float* Whh_b = (const float*)d_in[9];
  const float* b_b   = (const float*)d_in[10];
  const float* Wih_d = (const float*)d_in[11];
  const float* Whh_d = (const float*)d_in[12];
  const float* b_d   = (const float*)d_in[13];
  const float* W_h   = (const float*)d_in[14];
  const float* b_h   = (const float*)d_in[15];
  const float* W_c   = (const float*)d_in[16];
  const float* b_c   = (const float*)d_in[17];
  const float* W_df  = (const float*)d_in[18];
  const float* b_df  = (const float*)d_in[19];
  const float* W_ef  = (const float*)d_in[20];
  const float* b_ef  = (const float*)d_in[21];
  const float* W_out = (const float*)d_in[22];
  const float* b_out = (const float*)d_in[23];
  float* out = (float*)d_out;

  char* ws = (char*)d_ws;
  size_t off = 0;
  auto alloc = [&](size_t bytes) {
    char* p = ws + off;
    off += (bytes + 255) & ~(size_t)255;
    return p;
  };
  // --- zero-init group ---
  unsigned short* HBF  = (unsigned short*)alloc((size_t)2 * 2 * 16384 * 2);  // [dir][pp][32*512]
  float* DECH = (float*)alloc((size_t)16384 * 4);
  float* DECC = (float*)alloc((size_t)16384 * 4);
  unsigned short* PRE0 = (unsigned short*)alloc((size_t)32 * 1536 * 2);
  unsigned short* ACAT = (unsigned short*)alloc((size_t)1024 * 1536 * 2);
  unsigned* bar = (unsigned*)alloc(4096);  // 3 groups x 8 counters x 128 B
  size_t zbytes = off;
  // --- rest ---
  float* XF = (float*)alloc((size_t)2048 * 2048 * 4);
  float* XB = (float*)alloc((size_t)2048 * 2048 * 4);
  float* XD = (float*)alloc((size_t)1024 * 2048 * 4);
  unsigned short* EFb  = (unsigned short*)alloc((size_t)2048 * 1024 * 2);
  unsigned short* ENCO = (unsigned short*)alloc((size_t)2048 * 1024 * 2);
  unsigned short* EMBB = (unsigned short*)alloc((size_t)2048 * 256 * 2);
  unsigned short* DEMB = (unsigned short*)alloc((size_t)1024 * 256 * 2);
  float* HFIN = (float*)alloc((size_t)4 * 16384 * 4);
  // aliases (lifetimes: written after mega_enc consumed XF/XB)
  float* EFG = XF;   // 2048 x 1152 fp32
  float* WT  = XB;   // 1152 x 1024 fp32

  hipMemsetAsync(d_ws, 0, zbytes, stream);

  gather_enc_kernel<<<2048, 64, 0, stream>>>(enc_texts, enc_emb, EMBB);
  gather_dec_kernel<<<1024, 64, 0, stream>>>(dec_texts, dec_emb, DEMB);

  dim3 blk(256);
  gemm_bt_kernel<<<256, blk, 0, stream>>>(EMBB, 256, Wih_f, 256, 0, b_f, XF, 2048, 2048, 256, 16, 0, 0);
  gemm_bt_kernel<<<256, blk, 0, stream>>>(EMBB, 256, Wih_b, 256, 0, b_b, XB, 2048, 2048, 256, 16, 0, 0);
  gemm_bt_kernel<<<128, blk, 0, stream>>>(DEMB, 256, Wih_d, 1280, 0, b_d, XD, 2048, 1024, 256, 8, 0, 0);

  mega_enc_kernel<<<256, blk, 0, stream>>>(XF, XB, Whh_f, Whh_b, enc_mask, HBF, ENCO, HFIN, bar);

  wdf_t_kernel<<<1025, blk, 0, stream>>>(W_df, b_df, WT);
  gemm_bt_kernel<<<128, blk, 0, stream>>>(ENCO, 1024, W_ef, 1024, 0, b_ef, EFb, 1024, 2048, 1024, 16, 0, 1);
  gemm_bt_kernel<<<144, blk, 0, stream>>>(EFb, 1024, WT, 1024, 0, nullptr, EFG, 1152, 2048, 1024, 16, 0, 0);

  mega_dec_kernel<<<128, blk, 0, stream>>>(HFIN, W_h, b_h, W_c, b_c, XD, Wih_d, Whh_d,
                                           EFG, ENCO, enc_mask, DECH, DECC, PRE0, ACAT, bar + 512);

  // logits = [h, ctx] @ W_out^T + b_out  (97.5 GFLOP, XCD-swizzled)
  gemm_bt_kernel<<<2000, blk, 0, stream>>>(ACAT, 1536, W_out, 1536, 0, b_out, out, 32000, 992, 1536, 8, 1, 0);
}